// Round 5
// baseline (135.828 us; speedup 1.0000x reference)
//
#include <hip/hip_runtime.h>
#include <cstddef>
#include <cstdint>

// Problem constants: S=8, N=50000, F=5, DEG=32, D_IN=D_OUT=128
static constexpr int S_    = 8;
static constexpr int N_    = 50000;
static constexpr int F_    = 5;
static constexpr int DEG_  = 32;
static constexpr int DOUT_ = 128;
static constexpr int TOTAL_NODES = S_ * N_;                  // 400000
static constexpr int NODES_PER_GROUP = 8;                    // 4 chains x 2 halves
static constexpr int GROUPS = TOTAL_NODES / NODES_PER_GROUP; // 50000 (exact; N%8==0)
static constexpr int NWAVES = 4096;                          // 1024 blocks x 4 waves
static constexpr int KLO    = GROUPS / NWAVES;               // 12
static constexpr int RHI    = GROUPS - KLO * NWAVES;         // 848 waves get 13

typedef float    f32x4 __attribute__((ext_vector_type(4)));
typedef int      i32x2 __attribute__((ext_vector_type(2)));
typedef _Float16 h2    __attribute__((ext_vector_type(2)));

// ---------------------------------------------------------------------------
// Kernel 1: fuse W_1 [5][128] with W [256][128] into Wc [2][5][128].
// ---------------------------------------------------------------------------
__global__ void wc_precompute(const float* __restrict__ W1,
                              const float* __restrict__ W,
                              float* __restrict__ Wc) {
    int t = blockIdx.x * blockDim.x + threadIdx.x;
    if (t >= 2 * F_ * DOUT_) return;
    int o = t & (DOUT_ - 1);
    int f = (t >> 7) % F_;
    int p = t / (F_ * DOUT_);
    const float* w1r  = W1 + f * 128;
    const float* wcol = W + (size_t)p * 128 * DOUT_ + o;
    float acc = 0.f;
#pragma unroll 8
    for (int d = 0; d < 128; ++d)
        acc = fmaf(w1r[d], wcol[(size_t)d * DOUT_], acc);
    Wc[t] = acc;
}

// ---------------------------------------------------------------------------
// Kernel 2: pack x rows into 8B fp8-e4m3 rows (5 bytes used + pad).
// Table = 400000 * 8B = 3.2 MB -> fits a single XCD's 4 MB L2.
// ---------------------------------------------------------------------------
__global__ __launch_bounds__(256) void xpack_fp8(const float* __restrict__ x,
                                                 i32x2* __restrict__ xq) {
    int t = blockIdx.x * blockDim.x + threadIdx.x;
    if (t >= TOTAL_NODES) return;
    const float* r = x + (size_t)t * F_;
    int d0 = __builtin_amdgcn_cvt_pk_fp8_f32(r[0], r[1], 0, false);
    d0     = __builtin_amdgcn_cvt_pk_fp8_f32(r[2], r[3], d0, true);
    int d1 = __builtin_amdgcn_cvt_pk_fp8_f32(r[4], 0.f, 0, false);
    i32x2 v; v.x = d0; v.y = d1;
    xq[t] = v;
}

// ---------------------------------------------------------------------------
// Kernel 3: software-pipelined fused encoder.
//   One wave handles 12-13 consecutive groups of 8 nodes (4 chains x 2 halves).
//   3-stage pipeline per group: LOAD_IDX -> LOAD_GS (gather fp8 + self fp32)
//   -> COMPUTE (f16 butterfly + fused-weight MLP + relu + nt store).
//   Two register buffer sets (A/B), loop unrolled by 2 for static rotation.
// ---------------------------------------------------------------------------
#define LOAD_IDX(gg, nb)                                                     \
    { int base_ = (gg) * NODES_PER_GROUP;                                    \
      _Pragma("unroll")                                                      \
      for (int j = 0; j < 4; ++j) {                                          \
          int node_ = base_ + half + 2 * j;                                  \
          nb[j] = __builtin_nontemporal_load(idx + (size_t)node_ * DEG_ + sl); } }

#define LOAD_GS(gg, nb, gq, sa, s4)                                          \
    { int base_ = (gg) * NODES_PER_GROUP;                                    \
      const i32x2* xs_ = xq + (size_t)(base_ / N_) * N_;                     \
      _Pragma("unroll")                                                      \
      for (int j = 0; j < 4; ++j) gq[j] = xs_[nb[j]];          /* scattered 8B */ \
      _Pragma("unroll")                                                      \
      for (int j = 0; j < 4; ++j) {                                          \
          int node_ = base_ + half + 2 * j;                                  \
          __builtin_memcpy(&sa[j], x + (size_t)node_ * F_, 16); /* f0..f3 */ \
          s4[j] = x[(size_t)node_ * F_ + 4]; } }

#define COMPUTE(gg, gq, sa, s4)                                              \
    { int base_ = (gg) * NODES_PER_GROUP;                                    \
      _Pragma("unroll")                                                      \
      for (int j = 0; j < 4; ++j) {                                          \
          int d0_ = gq[j].x, d1_ = gq[j].y;                                  \
          float g0_ = __builtin_amdgcn_cvt_f32_fp8(d0_, 0);                  \
          float g1_ = __builtin_amdgcn_cvt_f32_fp8(d0_, 1);                  \
          float g2_ = __builtin_amdgcn_cvt_f32_fp8(d0_, 2);                  \
          float g3_ = __builtin_amdgcn_cvt_f32_fp8(d0_, 3);                  \
          float g4_ = __builtin_amdgcn_cvt_f32_fp8(d1_, 0);                  \
          h2 v0_ = { (_Float16)g0_, (_Float16)g1_ };                         \
          h2 v1_ = { (_Float16)g2_, (_Float16)g3_ };                         \
          h2 v2_ = { (_Float16)g4_, (_Float16)0.f };                         \
          _Pragma("unroll")                                                  \
          for (int m = 1; m < 32; m <<= 1) {                                 \
              v0_ += __builtin_bit_cast(h2, __shfl_xor(__builtin_bit_cast(int, v0_), m)); \
              v1_ += __builtin_bit_cast(h2, __shfl_xor(__builtin_bit_cast(int, v1_), m)); \
              v2_ += __builtin_bit_cast(h2, __shfl_xor(__builtin_bit_cast(int, v2_), m)); \
          }                                                                  \
          float nf_[F_] = { (float)v0_.x * inv, (float)v0_.y * inv,          \
                            (float)v1_.x * inv, (float)v1_.y * inv,          \
                            (float)v2_.x * inv };                            \
          float sf_[F_] = { sa[j].x, sa[j].y, sa[j].z, sa[j].w, s4[j] };     \
          float y0 = bias.x, y1 = bias.y, y2 = bias.z, y3 = bias.w;          \
          _Pragma("unroll")                                                  \
          for (int f = 0; f < F_; ++f) {                                     \
              y0 = fmaf(sf_[f], wa[f][0], y0); y0 = fmaf(nf_[f], wb[f][0], y0); \
              y1 = fmaf(sf_[f], wa[f][1], y1); y1 = fmaf(nf_[f], wb[f][1], y1); \
              y2 = fmaf(sf_[f], wa[f][2], y2); y2 = fmaf(nf_[f], wb[f][2], y2); \
              y3 = fmaf(sf_[f], wa[f][3], y3); y3 = fmaf(nf_[f], wb[f][3], y3); \
          }                                                                  \
          int node_ = base_ + half + 2 * j;                                  \
          f32x4 yv_ = { fmaxf(y0, 0.f), fmaxf(y1, 0.f),                      \
                        fmaxf(y2, 0.f), fmaxf(y3, 0.f) };                    \
          __builtin_nontemporal_store(yv_,                                   \
              reinterpret_cast<f32x4*>(out + (size_t)node_ * DOUT_ + o0));   \
      } }

__global__ __launch_bounds__(256) void encoder_v4(
    const int*   __restrict__ idx,   // [S][N][32]
    const i32x2* __restrict__ xq,    // [S*N] fp8-packed rows (gather source)
    const float* __restrict__ x,     // [S][N][5] fp32 (self features, exact)
    const float* __restrict__ Wc,    // [2][5][128]
    const float* __restrict__ b,     // [128]
    float* __restrict__ out) {       // [S][N][128]
    const int lane = threadIdx.x & 63;
    const int sl   = lane & 31;
    const int half = lane >> 5;
    const int o0   = sl << 2;
    const int w    = (blockIdx.x * blockDim.x + threadIdx.x) >> 6;  // 0..NWAVES-1

    // Contiguous per-wave group range: first RHI waves get KLO+1, rest KLO.
    const int g0   = (w < RHI) ? w * (KLO + 1) : RHI * (KLO + 1) + (w - RHI) * KLO;
    const int gend = g0 + ((w < RHI) ? (KLO + 1) : KLO);

    // Fused weights: loaded ONCE per wave (coalesced 16B/lane, L2-hot).
    float wa[F_][4], wb[F_][4];
#pragma unroll
    for (int f = 0; f < F_; ++f) {
        f32x4 a  = *reinterpret_cast<const f32x4*>(Wc + f * DOUT_ + o0);
        f32x4 bb = *reinterpret_cast<const f32x4*>(Wc + F_ * DOUT_ + f * DOUT_ + o0);
        wa[f][0] = a.x;  wa[f][1] = a.y;  wa[f][2] = a.z;  wa[f][3] = a.w;
        wb[f][0] = bb.x; wb[f][1] = bb.y; wb[f][2] = bb.z; wb[f][3] = bb.w;
    }
    const f32x4 bias = *reinterpret_cast<const f32x4*>(b + o0);
    const float inv = 1.f / DEG_;

    // Pipeline registers (A/B sets, static rotation via unroll-by-2).
    int   nbA[4], nbB[4];
    i32x2 gqA[4], gqB[4];
    f32x4 saA[4], saB[4];
    float s4A[4], s4B[4];

    // Prologue: idx for g0 and g0+1 in flight, then gathers for g0.
    LOAD_IDX(g0, nbA);
    LOAD_IDX(g0 + 1, nbB);           // gend - g0 >= 12, always valid
    LOAD_GS(g0, nbA, gqA, saA, s4A);

    for (int g = g0; g < gend; g += 2) {
        const int gp1 = (g + 1 < gend) ? g + 1 : gend - 1;   // clamp: redundant
        const int gp2 = (g + 2 < gend) ? g + 2 : gend - 1;   // loads, never OOB
        const int gp3 = (g + 3 < gend) ? g + 3 : gend - 1;

        LOAD_GS(gp1, nbB, gqB, saB, s4B);   // gathers for g+1 in flight
        LOAD_IDX(gp2, nbA);                 // idx for g+2 in flight
        COMPUTE(g, gqA, saA, s4A);          // covers the loads above

        LOAD_GS(gp2, nbA, gqA, saA, s4A);   // gathers for g+2 in flight
        LOAD_IDX(gp3, nbB);                 // idx for g+3 in flight
        if (g + 1 < gend) COMPUTE(gp1, gqB, saB, s4B);
    }
}

// ---------------------------------------------------------------------------
// Fallback (fp32 path) if ws_size is too small for the pack buffer.
// ---------------------------------------------------------------------------
__global__ __launch_bounds__(256) void encoder_f32(
    const float* __restrict__ x, const int* __restrict__ idx,
    const float* __restrict__ Wc, const float* __restrict__ b,
    float* __restrict__ out, int total_pairs) {
    const int lane = threadIdx.x & 63;
    const int sl   = lane & 31;
    const int half = lane >> 5;
    const int o0   = sl << 2;
    const int gwave  = (blockIdx.x * blockDim.x + threadIdx.x) >> 6;
    const int nwaves = (gridDim.x * blockDim.x) >> 6;
    float wa[F_][4], wb[F_][4];
#pragma unroll
    for (int f = 0; f < F_; ++f) {
        f32x4 a  = *reinterpret_cast<const f32x4*>(Wc + f * DOUT_ + o0);
        f32x4 bb = *reinterpret_cast<const f32x4*>(Wc + F_ * DOUT_ + f * DOUT_ + o0);
        wa[f][0] = a.x;  wa[f][1] = a.y;  wa[f][2] = a.z;  wa[f][3] = a.w;
        wb[f][0] = bb.x; wb[f][1] = bb.y; wb[f][2] = bb.z; wb[f][3] = bb.w;
    }
    const f32x4 bias = *reinterpret_cast<const f32x4*>(b + o0);
    for (int p = gwave; p < total_pairs; p += nwaves) {
        const int node = p * 2 + half;
        const int s    = node / N_;
        const int nb = idx[(size_t)node * DEG_ + sl];
        const float* xr = x + ((size_t)s * N_ + nb) * F_;
        float n0 = xr[0], n1 = xr[1], n2 = xr[2], n3 = xr[3], n4 = xr[4];
#pragma unroll
        for (int m = 1; m < 32; m <<= 1) {
            n0 += __shfl_xor(n0, m); n1 += __shfl_xor(n1, m); n2 += __shfl_xor(n2, m);
            n3 += __shfl_xor(n3, m); n4 += __shfl_xor(n4, m);
        }
        const float inv = 1.f / DEG_;
        const float nf[F_] = {n0 * inv, n1 * inv, n2 * inv, n3 * inv, n4 * inv};
        const float* xsp = x + (size_t)node * F_;
        const float sf[F_] = {xsp[0], xsp[1], xsp[2], xsp[3], xsp[4]};
        float y0 = bias.x, y1 = bias.y, y2 = bias.z, y3 = bias.w;
#pragma unroll
        for (int f = 0; f < F_; ++f) {
            y0 = fmaf(sf[f], wa[f][0], y0); y0 = fmaf(nf[f], wb[f][0], y0);
            y1 = fmaf(sf[f], wa[f][1], y1); y1 = fmaf(nf[f], wb[f][1], y1);
            y2 = fmaf(sf[f], wa[f][2], y2); y2 = fmaf(nf[f], wb[f][2], y2);
            y3 = fmaf(sf[f], wa[f][3], y3); y3 = fmaf(nf[f], wb[f][3], y3);
        }
        f32x4 yv = { fmaxf(y0, 0.f), fmaxf(y1, 0.f), fmaxf(y2, 0.f), fmaxf(y3, 0.f) };
        *reinterpret_cast<f32x4*>(out + (size_t)node * DOUT_ + o0) = yv;
    }
}

extern "C" void kernel_launch(void* const* d_in, const int* in_sizes, int n_in,
                              void* d_out, int out_size, void* d_ws, size_t ws_size,
                              hipStream_t stream) {
    const float* x   = (const float*)d_in[0];
    const int*   idx = (const int*)  d_in[1];
    const float* W1  = (const float*)d_in[2];
    const float* W   = (const float*)d_in[3];
    const float* b   = (const float*)d_in[4];
    float* out = (float*)d_out;

    const size_t wc_bytes = (size_t)2 * F_ * DOUT_ * sizeof(float);   // 5120
    const size_t xq_bytes = (size_t)TOTAL_NODES * sizeof(i32x2);      // 3.2 MB
    float* Wc = (float*)d_ws;

    hipLaunchKernelGGL(wc_precompute, dim3(5), dim3(256), 0, stream, W1, W, Wc);

    if (ws_size >= wc_bytes + xq_bytes) {
        i32x2* xq = (i32x2*)((char*)d_ws + wc_bytes);   // 5120 % 8 == 0
        hipLaunchKernelGGL(xpack_fp8, dim3((TOTAL_NODES + 255) / 256), dim3(256),
                           0, stream, x, xq);
        hipLaunchKernelGGL(encoder_v4, dim3(NWAVES / 4), dim3(256), 0, stream,
                           idx, xq, x, Wc, b, out);
    } else {
        hipLaunchKernelGGL(encoder_f32, dim3(2048), dim3(256), 0, stream,
                           x, idx, Wc, b, out, TOTAL_NODES / 2);
    }
}

// Round 6
// 115.355 us; speedup vs baseline: 1.1775x; 1.1775x over previous
//
#include <hip/hip_runtime.h>
#include <cstddef>
#include <cstdint>

// Problem constants: S=8, N=50000, F=5, DEG=32, D_IN=D_OUT=128
static constexpr int S_    = 8;
static constexpr int N_    = 50000;
static constexpr int F_    = 5;
static constexpr int DEG_  = 32;
static constexpr int DOUT_ = 128;
static constexpr int TOTAL_NODES = S_ * N_;                   // 400000
static constexpr int NODES_PER_WAVE = 16;                     // 8 chains x 2 halves
static constexpr int GROUPS = TOTAL_NODES / NODES_PER_WAVE;   // 25000 (16 | 50000)

typedef float    f32x4 __attribute__((ext_vector_type(4)));
typedef int      i32x2 __attribute__((ext_vector_type(2)));
typedef int      i32x4 __attribute__((ext_vector_type(4)));
typedef _Float16 h2    __attribute__((ext_vector_type(2)));

// ---------------------------------------------------------------------------
// Kernel 1: fuse W_1 [5][128] with W [256][128] into Wc [2][5][128].
// ---------------------------------------------------------------------------
__global__ void wc_precompute(const float* __restrict__ W1,
                              const float* __restrict__ W,
                              float* __restrict__ Wc) {
    int t = blockIdx.x * blockDim.x + threadIdx.x;
    if (t >= 2 * F_ * DOUT_) return;
    int o = t & (DOUT_ - 1);
    int f = (t >> 7) % F_;
    int p = t / (F_ * DOUT_);
    const float* w1r  = W1 + f * 128;
    const float* wcol = W + (size_t)p * 128 * DOUT_ + o;
    float acc = 0.f;
#pragma unroll 8
    for (int d = 0; d < 128; ++d)
        acc = fmaf(w1r[d], wcol[(size_t)d * DOUT_], acc);
    Wc[t] = acc;
}

// ---------------------------------------------------------------------------
// Kernel 2a: pack x rows into 8B fp8-e4m3 rows. Table = 3.2 MB -> fits the
// 4 MB per-XCD L2, killing the L2<-L3 128B-line amplification on gathers.
// ---------------------------------------------------------------------------
__global__ __launch_bounds__(256) void xpack_fp8(const float* __restrict__ x,
                                                 i32x2* __restrict__ xq) {
    int t = blockIdx.x * blockDim.x + threadIdx.x;
    if (t >= TOTAL_NODES) return;
    const float* r = x + (size_t)t * F_;
    int d0 = __builtin_amdgcn_cvt_pk_fp8_f32(r[0], r[1], 0, false);
    d0     = __builtin_amdgcn_cvt_pk_fp8_f32(r[2], r[3], d0, true);
    int d1 = __builtin_amdgcn_cvt_pk_fp8_f32(r[4], 0.f, 0, false);
    i32x2 v; v.x = d0; v.y = d1;
    xq[t] = v;
}

// ---------------------------------------------------------------------------
// Kernel 2b: pack x rows into 16B f16 rows (self-feature path, coalesced).
// ---------------------------------------------------------------------------
struct alignas(16) H8 { _Float16 v[8]; };

__global__ __launch_bounds__(256) void xpack_f16(const float* __restrict__ x,
                                                 H8* __restrict__ xh) {
    int t = blockIdx.x * blockDim.x + threadIdx.x;
    if (t >= TOTAL_NODES) return;
    const float* r = x + (size_t)t * F_;
    H8 o;
#pragma unroll
    for (int f = 0; f < F_; ++f) o.v[f] = (_Float16)r[f];
#pragma unroll
    for (int f = F_; f < 8; ++f) o.v[f] = (_Float16)0.f;
    xh[t] = o;
}

// ---------------------------------------------------------------------------
// Kernel 3: fused encoder v6. Round-4 structure (exact dispatch, all loads
// issued up front) widened to 8 independent chains = 16 nodes per wave.
// Gathers read the L2-resident 3.2MB fp8 table; self features from f16 table.
// ---------------------------------------------------------------------------
__global__ __launch_bounds__(256) void encoder_v6(
    const int*   __restrict__ idx,   // [S][N][32]
    const i32x2* __restrict__ xq,    // [S*N] fp8 rows (gather, L2-hot)
    const H8*    __restrict__ xh,    // [S*N] f16 rows (self, broadcast)
    const float* __restrict__ Wc,    // [2][5][128]
    const float* __restrict__ b,     // [128]
    float* __restrict__ out) {       // [S][N][128]
    const int lane = threadIdx.x & 63;
    const int sl   = lane & 31;
    const int half = lane >> 5;
    const int o0   = sl << 2;
    const int g    = (blockIdx.x * blockDim.x + threadIdx.x) >> 6;  // 0..24999

    // Fused weights: 11 coalesced 16B loads per lane, once per 16 nodes.
    float wa[F_][4], wb[F_][4];
#pragma unroll
    for (int f = 0; f < F_; ++f) {
        f32x4 a  = *reinterpret_cast<const f32x4*>(Wc + f * DOUT_ + o0);
        f32x4 bb = *reinterpret_cast<const f32x4*>(Wc + F_ * DOUT_ + f * DOUT_ + o0);
        wa[f][0] = a.x;  wa[f][1] = a.y;  wa[f][2] = a.z;  wa[f][3] = a.w;
        wb[f][0] = bb.x; wb[f][1] = bb.y; wb[f][2] = bb.z; wb[f][3] = bb.w;
    }
    const f32x4 bias = *reinterpret_cast<const f32x4*>(b + o0);
    const float inv = 1.f / DEG_;

    const int base = g * NODES_PER_WAVE;
    const int s    = base / N_;                  // uniform (16 | 50000)
    const i32x2* xs = xq + (size_t)s * N_;

    // --- issue ALL loads up front: 8 idx, 8 gathers, 8 self rows ---
    int nb[8];
#pragma unroll
    for (int j = 0; j < 8; ++j) {
        const int node = base + 2 * j + half;
        nb[j] = __builtin_nontemporal_load(idx + (size_t)node * DEG_ + sl);
    }
    i32x2 gq[8];
#pragma unroll
    for (int j = 0; j < 8; ++j) gq[j] = xs[nb[j]];               // scattered 8B, L2
    union US { i32x4 i; h2 h[4]; } sv[8];
#pragma unroll
    for (int j = 0; j < 8; ++j) {
        const int node = base + 2 * j + half;
        sv[j].i = *reinterpret_cast<const i32x4*>(xh + node);    // broadcast 16B
    }

    // --- per chain: fp8->f16 unpack, butterfly, MLP, relu, nt store ---
#pragma unroll
    for (int j = 0; j < 8; ++j) {
        const int d0 = gq[j].x, d1 = gq[j].y;
        const float g0 = __builtin_amdgcn_cvt_f32_fp8(d0, 0);
        const float g1 = __builtin_amdgcn_cvt_f32_fp8(d0, 1);
        const float g2 = __builtin_amdgcn_cvt_f32_fp8(d0, 2);
        const float g3 = __builtin_amdgcn_cvt_f32_fp8(d0, 3);
        const float g4 = __builtin_amdgcn_cvt_f32_fp8(d1, 0);
        h2 v0 = { (_Float16)g0, (_Float16)g1 };
        h2 v1 = { (_Float16)g2, (_Float16)g3 };
        h2 v2 = { (_Float16)g4, (_Float16)0.f };
#pragma unroll
        for (int m = 1; m < 32; m <<= 1) {
            v0 += __builtin_bit_cast(h2, __shfl_xor(__builtin_bit_cast(int, v0), m));
            v1 += __builtin_bit_cast(h2, __shfl_xor(__builtin_bit_cast(int, v1), m));
            v2 += __builtin_bit_cast(h2, __shfl_xor(__builtin_bit_cast(int, v2), m));
        }
        const float nf[F_] = { (float)v0.x * inv, (float)v0.y * inv,
                               (float)v1.x * inv, (float)v1.y * inv,
                               (float)v2.x * inv };
        const float sf[F_] = { (float)sv[j].h[0].x, (float)sv[j].h[0].y,
                               (float)sv[j].h[1].x, (float)sv[j].h[1].y,
                               (float)sv[j].h[2].x };
        float y0 = bias.x, y1 = bias.y, y2 = bias.z, y3 = bias.w;
#pragma unroll
        for (int f = 0; f < F_; ++f) {
            y0 = fmaf(sf[f], wa[f][0], y0); y0 = fmaf(nf[f], wb[f][0], y0);
            y1 = fmaf(sf[f], wa[f][1], y1); y1 = fmaf(nf[f], wb[f][1], y1);
            y2 = fmaf(sf[f], wa[f][2], y2); y2 = fmaf(nf[f], wb[f][2], y2);
            y3 = fmaf(sf[f], wa[f][3], y3); y3 = fmaf(nf[f], wb[f][3], y3);
        }
        const int node = base + 2 * j + half;
        f32x4 yv = { fmaxf(y0, 0.f), fmaxf(y1, 0.f), fmaxf(y2, 0.f), fmaxf(y3, 0.f) };
        __builtin_nontemporal_store(yv,
            reinterpret_cast<f32x4*>(out + (size_t)node * DOUT_ + o0));
    }
}

// ---------------------------------------------------------------------------
// Fallback (fp32 path) if ws_size is too small for the pack buffers.
// ---------------------------------------------------------------------------
__global__ __launch_bounds__(256) void encoder_f32(
    const float* __restrict__ x, const int* __restrict__ idx,
    const float* __restrict__ Wc, const float* __restrict__ b,
    float* __restrict__ out, int total_pairs) {
    const int lane = threadIdx.x & 63;
    const int sl   = lane & 31;
    const int half = lane >> 5;
    const int o0   = sl << 2;
    const int gwave  = (blockIdx.x * blockDim.x + threadIdx.x) >> 6;
    const int nwaves = (gridDim.x * blockDim.x) >> 6;
    float wa[F_][4], wb[F_][4];
#pragma unroll
    for (int f = 0; f < F_; ++f) {
        f32x4 a  = *reinterpret_cast<const f32x4*>(Wc + f * DOUT_ + o0);
        f32x4 bb = *reinterpret_cast<const f32x4*>(Wc + F_ * DOUT_ + f * DOUT_ + o0);
        wa[f][0] = a.x;  wa[f][1] = a.y;  wa[f][2] = a.z;  wa[f][3] = a.w;
        wb[f][0] = bb.x; wb[f][1] = bb.y; wb[f][2] = bb.z; wb[f][3] = bb.w;
    }
    const f32x4 bias = *reinterpret_cast<const f32x4*>(b + o0);
    for (int p = gwave; p < total_pairs; p += nwaves) {
        const int node = p * 2 + half;
        const int s    = node / N_;
        const int nb = idx[(size_t)node * DEG_ + sl];
        const float* xr = x + ((size_t)s * N_ + nb) * F_;
        float n0 = xr[0], n1 = xr[1], n2 = xr[2], n3 = xr[3], n4 = xr[4];
#pragma unroll
        for (int m = 1; m < 32; m <<= 1) {
            n0 += __shfl_xor(n0, m); n1 += __shfl_xor(n1, m); n2 += __shfl_xor(n2, m);
            n3 += __shfl_xor(n3, m); n4 += __shfl_xor(n4, m);
        }
        const float inv = 1.f / DEG_;
        const float nf[F_] = {n0 * inv, n1 * inv, n2 * inv, n3 * inv, n4 * inv};
        const float* xsp = x + (size_t)node * F_;
        const float sf[F_] = {xsp[0], xsp[1], xsp[2], xsp[3], xsp[4]};
        float y0 = bias.x, y1 = bias.y, y2 = bias.z, y3 = bias.w;
#pragma unroll
        for (int f = 0; f < F_; ++f) {
            y0 = fmaf(sf[f], wa[f][0], y0); y0 = fmaf(nf[f], wb[f][0], y0);
            y1 = fmaf(sf[f], wa[f][1], y1); y1 = fmaf(nf[f], wb[f][1], y1);
            y2 = fmaf(sf[f], wa[f][2], y2); y2 = fmaf(nf[f], wb[f][2], y2);
            y3 = fmaf(sf[f], wa[f][3], y3); y3 = fmaf(nf[f], wb[f][3], y3);
        }
        f32x4 yv = { fmaxf(y0, 0.f), fmaxf(y1, 0.f), fmaxf(y2, 0.f), fmaxf(y3, 0.f) };
        *reinterpret_cast<f32x4*>(out + (size_t)node * DOUT_ + o0) = yv;
    }
}

extern "C" void kernel_launch(void* const* d_in, const int* in_sizes, int n_in,
                              void* d_out, int out_size, void* d_ws, size_t ws_size,
                              hipStream_t stream) {
    const float* x   = (const float*)d_in[0];
    const int*   idx = (const int*)  d_in[1];
    const float* W1  = (const float*)d_in[2];
    const float* W   = (const float*)d_in[3];
    const float* b   = (const float*)d_in[4];
    float* out = (float*)d_out;

    const size_t wc_bytes = (size_t)2 * F_ * DOUT_ * sizeof(float);   // 5120
    const size_t xq_bytes = (size_t)TOTAL_NODES * sizeof(i32x2);      // 3.2 MB
    const size_t xh_bytes = (size_t)TOTAL_NODES * sizeof(H8);         // 6.4 MB
    float* Wc = (float*)d_ws;

    hipLaunchKernelGGL(wc_precompute, dim3(5), dim3(256), 0, stream, W1, W, Wc);

    if (ws_size >= wc_bytes + xq_bytes + xh_bytes) {
        i32x2* xq = (i32x2*)((char*)d_ws + wc_bytes);
        H8*    xh = (H8*)   ((char*)d_ws + wc_bytes + xq_bytes);  // 16B-aligned
        hipLaunchKernelGGL(xpack_fp8, dim3((TOTAL_NODES + 255) / 256), dim3(256),
                           0, stream, x, xq);
        hipLaunchKernelGGL(xpack_f16, dim3((TOTAL_NODES + 255) / 256), dim3(256),
                           0, stream, x, xh);
        // Exact dispatch: 25000 waves, 4 waves/block -> 6250 blocks.
        hipLaunchKernelGGL(encoder_v6, dim3(GROUPS / 4), dim3(256), 0, stream,
                           idx, xq, xh, Wc, b, out);
    } else {
        hipLaunchKernelGGL(encoder_f32, dim3(2048), dim3(256), 0, stream,
                           x, idx, Wc, b, out, TOTAL_NODES / 2);
    }
}